// Round 1
// baseline (38.450 us; speedup 1.0000x reference)
//
#include <hip/hip_runtime.h>

// ContrastiveLoss: reference collapses to
//   v = sum_i mask_i * latent_i / max(||latent_i||, eps)   (64-vector)
//   out = COF1 * (||v||^2 - sum(mask)) / (2N)
// O(N*d) instead of O(N^2*d).

#define EPSV 1e-8f
#define COF1 0.01f

constexpr int N_ROWS = 8192;
constexpr int DIM = 64;
constexpr int WAVES_TOTAL = 128;                 // each wave handles 64 rows
constexpr int ROWS_PER_WAVE = N_ROWS / WAVES_TOTAL;

// Kernel 1: per-wave partial accumulation of v (64 floats) + mask count.
// Wave w writes ws[w*65 .. w*65+64] fully (no zero-init of ws required).
__global__ __launch_bounds__(256) void cl_partial(const float* __restrict__ latent,
                                                  float* __restrict__ ws) {
    const int wave = (blockIdx.x * blockDim.x + threadIdx.x) >> 6;
    const int lane = threadIdx.x & 63;
    const int row0 = wave * ROWS_PER_WAVE;

    float v = 0.0f;   // partial of v[lane]
    float cnt = 0.0f; // partial of sum(mask)

    for (int r = 0; r < ROWS_PER_WAVE; ++r) {
        // wave reads one full row: lane l -> element l (perfectly coalesced)
        float x = latent[(long)(row0 + r) * DIM + lane];
        float s = x;       // row sum   (mask test)
        float q = x * x;   // row sumsq (norm)
        #pragma unroll
        for (int off = 32; off; off >>= 1) {
            s += __shfl_xor(s, off);
            q += __shfl_xor(q, off);
        }
        // all 64 lanes now hold the full row sum / sumsq
        if (s != 0.0f) {
            v += x * (1.0f / fmaxf(sqrtf(q), EPSV));
            cnt += 1.0f;
        }
    }

    float* slot = ws + wave * (DIM + 1);
    slot[lane] = v;
    if (lane == 0) slot[DIM] = cnt;
}

// Kernel 2: one wave reduces the 128 partial slots and finalizes.
__global__ __launch_bounds__(64) void cl_final(const float* __restrict__ ws,
                                               float* __restrict__ out) {
    const int lane = threadIdx.x;  // 64 threads = 1 wave
    float acc = 0.0f;  // v[lane]
    float c   = 0.0f;  // total count (every lane computes the same value)
    for (int b = 0; b < WAVES_TOTAL; ++b) {
        acc += ws[b * (DIM + 1) + lane];
        c   += ws[b * (DIM + 1) + DIM];
    }
    float d = acc * acc;
    #pragma unroll
    for (int off = 32; off; off >>= 1) {
        d += __shfl_xor(d, off);
    }
    if (lane == 0) {
        float total = d - c;  // ||v||^2 - sum(mask)
        out[0] = COF1 * total / (2.0f * (float)N_ROWS);
    }
}

extern "C" void kernel_launch(void* const* d_in, const int* in_sizes, int n_in,
                              void* d_out, int out_size, void* d_ws, size_t ws_size,
                              hipStream_t stream) {
    const float* latent = (const float*)d_in[0];
    float* out = (float*)d_out;
    float* ws = (float*)d_ws;   // needs 128*65*4 = 33280 bytes

    cl_partial<<<WAVES_TOTAL * 64 / 256, 256, 0, stream>>>(latent, ws);
    cl_final<<<1, 64, 0, stream>>>(ws, out);
}